// Round 14
// baseline (93.561 us; speedup 1.0000x reference)
//
#include <hip/hip_runtime.h>
#include <hip/hip_bf16.h>

constexpr int B  = 256;
constexpr int E  = 16384;
constexpr int M  = 65536;
constexpr int H  = 128;
constexpr int NH = 4;
constexpr int HD = 32;
constexpr int LQ = 128;
constexpr int LK = 384;

// bf16 weight buffer offsets (elements)
constexpr int WQ_OFF  = 0;
constexpr int WK_OFF  = 16384;
constexpr int WV_OFF  = 32768;
constexpr int OPW_OFF = 49152;
constexpr int W1_OFF  = 65536;
constexpr int W2_OFF  = 98304;
constexpr int W_TOTAL = 131072;

typedef __attribute__((ext_vector_type(8))) short bf16x8;
typedef __attribute__((ext_vector_type(8))) unsigned short u16x8;
typedef __attribute__((ext_vector_type(4))) float f32x4;

__device__ __forceinline__ ushort f2bf(float x) {
  union { float f; unsigned u; } v; v.f = x;
  unsigned r = (v.u + 0x7FFFu + ((v.u >> 16) & 1u)) >> 16;
  return (ushort)r;
}

// ---------------- K1: starts + bf16 weights + bf16 edge_attr copy ----------------
__global__ __launch_bounds__(256) void k_starts_prep(
    const int* __restrict__ eb, const int* __restrict__ ieb,
    int* __restrict__ sq, int* __restrict__ sk,
    const float* __restrict__ in_proj_w, const float* __restrict__ opw,
    const float* __restrict__ w1, const float* __restrict__ w2,
    const float* __restrict__ edge_attr,
    ushort* __restrict__ Wb, ushort* __restrict__ Eb) {
  const int bx = blockIdx.x, t = threadIdx.x;
  if (bx == 0) {
    for (int i = t; i <= B; i += 256) {
      int lo = 0, hi = E;
      while (lo < hi) { int mid = (lo + hi) >> 1; if (eb[mid] < i) lo = mid + 1; else hi = mid; }
      sq[i] = lo;
      lo = 0; hi = M;
      while (lo < hi) { int mid = (lo + hi) >> 1; if (ieb[mid] < i) lo = mid + 1; else hi = mid; }
      sk[i] = lo;
    }
  } else if (bx <= 128) {
    int i = ((bx - 1) * 256 + t) * 4;
    if (i < W_TOTAL) {
      float4 v;
      if (i < OPW_OFF)      v = *(const float4*)(in_proj_w + i);
      else if (i < W1_OFF)  v = *(const float4*)(opw + (i - OPW_OFF));
      else if (i < W2_OFF)  v = *(const float4*)(w1 + (i - W1_OFF));
      else                  v = *(const float4*)(w2 + (i - W2_OFF));
      ushort4 o; o.x = f2bf(v.x); o.y = f2bf(v.y); o.z = f2bf(v.z); o.w = f2bf(v.w);
      *(ushort4*)(Wb + i) = o;
    }
  } else {
    int i = ((bx - 129) * 256 + t) * 4;   // E*H = 2M elems, 2048 blocks
    float4 v = *(const float4*)(edge_attr + i);
    ushort4 o; o.x = f2bf(v.x); o.y = f2bf(v.y); o.z = f2bf(v.z); o.w = f2bf(v.w);
    *(ushort4*)(Eb + i) = o;
  }
}

// ---------------- K2: fused QKV-projection + flash attention ----------------
// grid (B, NH), 512 threads = 8 waves. Wave w owns q-tile w (nqt<=8): no
// flash-phase barriers, no merge. Chunk = 64 keys with K-frag prefetch.
__global__ __launch_bounds__(512, 2) void k_attn_fused(
    const ushort* __restrict__ Eb, const int* __restrict__ iel,
    const ushort* __restrict__ Wb, const float* __restrict__ in_proj_b,
    const int* __restrict__ sq, const int* __restrict__ sk,
    ushort* __restrict__ CtxB) {
  constexpr int KP = 36;
  constexpr int QP = 40;
  constexpr int VP = 388;
  constexpr int PPW = 1088;  // per-wave P region (16 rows x pitch 68)
  __shared__ ushort Kl[LK * KP];               // 27648 B
  __shared__ __align__(16) ushort UQP[8 * PPW];// 17408 B: Ql (proj) then per-wave P
  __shared__ ushort VTl[HD * VP];              // 24832 B

  const int b = blockIdx.x, h = blockIdx.y;
  const int t = threadIdx.x;
  const int q0 = sq[b], lenq = sq[b + 1] - q0;
  const int k0 = sk[b], lenk = sk[b + 1] - k0;
  const int nq = lenq < LQ ? lenq : LQ;
  const int nk = lenk < LK ? lenk : LK;
  const int nkc = (nk + 63) & ~63;     // 64-granular padding
  const int nqt = (nq + 15) >> 4;
  const int nkt = nkc >> 4;

  const int w = t >> 6, lane = t & 63, g = lane >> 4, l15 = lane & 15;
  const int chb = h * HD;               // head channel base (32 ch)
  const ushort4 z4 = {0, 0, 0, 0};

  // ---- Q projection: wave w handles q-tile w (nqt <= 8) ----
  if (w < nqt) {
    bf16x8 wf[2][4];
#pragma unroll
    for (int ct = 0; ct < 2; ct++)
#pragma unroll
      for (int kc = 0; kc < 4; kc++)
        wf[ct][kc] = *(const bf16x8*)(Wb + WQ_OFF + (size_t)(chb + ct * 16 + l15) * H + kc * 32 + g * 8);
    int slot = w * 16 + l15;
    bool valid = slot < nq;
    int src = q0 + slot;
    if (lenq > LQ && slot == LQ - 1) src = q0 + lenq - 1;
    if (!valid) src = q0;
    bf16x8 rb[4];
#pragma unroll
    for (int kc = 0; kc < 4; kc++)
      rb[kc] = *(const bf16x8*)(Eb + (size_t)src * H + kc * 32 + g * 8);
#pragma unroll
    for (int ct = 0; ct < 2; ct++) {
      f32x4 acc = {0.f, 0.f, 0.f, 0.f};
#pragma unroll
      for (int kc = 0; kc < 4; kc++)
        acc = __builtin_amdgcn_mfma_f32_16x16x32_bf16(wf[ct][kc], rb[kc], acc, 0, 0, 0);
      ushort4 v = z4;
      if (valid) {
        float4 bb = *(const float4*)(in_proj_b + chb + ct * 16 + 4 * g);
        v.x = f2bf(acc[0] + bb.x); v.y = f2bf(acc[1] + bb.y);
        v.z = f2bf(acc[2] + bb.z); v.w = f2bf(acc[3] + bb.w);
      }
      *(ushort4*)(UQP + (w * 16 + l15) * QP + ct * 16 + 4 * g) = v;
    }
  }

  // ---- K,V projection: kt tiles split across 8 waves ----
  {
    bf16x8 wkf[2][4], wvf[2][4];
#pragma unroll
    for (int ct = 0; ct < 2; ct++)
#pragma unroll
      for (int kc = 0; kc < 4; kc++) {
        wkf[ct][kc] = *(const bf16x8*)(Wb + WK_OFF + (size_t)(chb + ct * 16 + l15) * H + kc * 32 + g * 8);
        wvf[ct][kc] = *(const bf16x8*)(Wb + WV_OFF + (size_t)(chb + ct * 16 + l15) * H + kc * 32 + g * 8);
      }
    for (int kt = w; kt < nkt; kt += 8) {
      int slot = kt * 16 + l15;
      bool valid = slot < nk;
      int src = 0;
      if (valid) {
        int kj = k0 + slot;
        if (lenk > LK && slot == LK - 1) kj = k0 + lenk - 1;
        src = iel[kj];
      }
      bf16x8 rb[4];
#pragma unroll
      for (int kc = 0; kc < 4; kc++)
        rb[kc] = *(const bf16x8*)(Eb + (size_t)src * H + kc * 32 + g * 8);
      // K -> Kl row-major
#pragma unroll
      for (int ct = 0; ct < 2; ct++) {
        f32x4 acc = {0.f, 0.f, 0.f, 0.f};
#pragma unroll
        for (int kc = 0; kc < 4; kc++)
          acc = __builtin_amdgcn_mfma_f32_16x16x32_bf16(wkf[ct][kc], rb[kc], acc, 0, 0, 0);
        ushort4 v = z4;
        if (valid) {
          float4 bb = *(const float4*)(in_proj_b + H + chb + ct * 16 + 4 * g);
          v.x = f2bf(acc[0] + bb.x); v.y = f2bf(acc[1] + bb.y);
          v.z = f2bf(acc[2] + bb.z); v.w = f2bf(acc[3] + bb.w);
        }
        *(ushort4*)(Kl + (kt * 16 + l15) * KP + ct * 16 + 4 * g) = v;
      }
      // V -> VTl transposed (channel rows)
#pragma unroll
      for (int ct = 0; ct < 2; ct++) {
        f32x4 acc = {0.f, 0.f, 0.f, 0.f};
#pragma unroll
        for (int kc = 0; kc < 4; kc++)
          acc = __builtin_amdgcn_mfma_f32_16x16x32_bf16(wvf[ct][kc], rb[kc], acc, 0, 0, 0);
        if (valid) {
          float4 bb = *(const float4*)(in_proj_b + 2 * H + chb + ct * 16 + 4 * g);
          VTl[(ct * 16 + 4 * g + 0) * VP + kt * 16 + l15] = f2bf(acc[0] + bb.x);
          VTl[(ct * 16 + 4 * g + 1) * VP + kt * 16 + l15] = f2bf(acc[1] + bb.y);
          VTl[(ct * 16 + 4 * g + 2) * VP + kt * 16 + l15] = f2bf(acc[2] + bb.z);
          VTl[(ct * 16 + 4 * g + 3) * VP + kt * 16 + l15] = f2bf(acc[3] + bb.w);
        } else {
#pragma unroll
          for (int r = 0; r < 4; r++)
            VTl[(ct * 16 + 4 * g + r) * VP + kt * 16 + l15] = 0;
        }
      }
    }
  }
  __syncthreads();

  // hoist this wave's Q B-fragment (UQP re-used for P after next barrier)
  bf16x8 bq = {};
  if (w < nqt) bq = *(const bf16x8*)(UQP + (w * 16 + l15) * QP + g * 8);
  __syncthreads();

  // ---- flash attention: wave w owns q-tile w; no block barriers ----
  if (w < nqt) {
    ushort* Pw = UQP + w * PPW;            // 16 rows x pitch 68
    const float scale = 0.17677669529663687f;  // 1/sqrt(32)
    f32x4 o0 = {0.f, 0.f, 0.f, 0.f}, o1 = {0.f, 0.f, 0.f, 0.f};
    float m = -3.0e38f, s = 0.f;
    bf16x8 a0 = {}, a1 = {}, a2 = {}, a3 = {};
    if (nk > 0) {
      a0 = *(const bf16x8*)(Kl + (l15) * KP + g * 8);
      a1 = *(const bf16x8*)(Kl + (16 + l15) * KP + g * 8);
      a2 = *(const bf16x8*)(Kl + (32 + l15) * KP + g * 8);
      a3 = *(const bf16x8*)(Kl + (48 + l15) * KP + g * 8);
    }
    for (int kc = 0; kc < nk; kc += 64) {
      f32x4 z = {0.f, 0.f, 0.f, 0.f};
      f32x4 st0 = __builtin_amdgcn_mfma_f32_16x16x32_bf16(a0, bq, z, 0, 0, 0);
      f32x4 st1 = __builtin_amdgcn_mfma_f32_16x16x32_bf16(a1, bq, z, 0, 0, 0);
      f32x4 st2 = __builtin_amdgcn_mfma_f32_16x16x32_bf16(a2, bq, z, 0, 0, 0);
      f32x4 st3 = __builtin_amdgcn_mfma_f32_16x16x32_bf16(a3, bq, z, 0, 0, 0);
      // prefetch next chunk's K A-frags (independent; hides under softmax)
      if (kc + 64 < nk) {
        a0 = *(const bf16x8*)(Kl + (kc + 64 + l15) * KP + g * 8);
        a1 = *(const bf16x8*)(Kl + (kc + 80 + l15) * KP + g * 8);
        a2 = *(const bf16x8*)(Kl + (kc + 96 + l15) * KP + g * 8);
        a3 = *(const bf16x8*)(Kl + (kc + 112 + l15) * KP + g * 8);
      }
      float p[16];
#pragma unroll
      for (int r = 0; r < 4; r++) {
        p[r]      = (kc + 4 * g + r < nk)      ? st0[r] * scale : -1e30f;
        p[4 + r]  = (kc + 16 + 4 * g + r < nk) ? st1[r] * scale : -1e30f;
        p[8 + r]  = (kc + 32 + 4 * g + r < nk) ? st2[r] * scale : -1e30f;
        p[12 + r] = (kc + 48 + 4 * g + r < nk) ? st3[r] * scale : -1e30f;
      }
      float pm = p[0];
#pragma unroll
      for (int r = 1; r < 16; r++) pm = fmaxf(pm, p[r]);
      pm = fmaxf(pm, __shfl_xor(pm, 16));
      pm = fmaxf(pm, __shfl_xor(pm, 32));
      float mn = fmaxf(m, pm);
      float corr = __expf(m - mn);
      float rs = 0.f;
#pragma unroll
      for (int r = 0; r < 16; r++) { p[r] = __expf(p[r] - mn); rs += p[r]; }
      rs += __shfl_xor(rs, 16);
      rs += __shfl_xor(rs, 32);
      s = s * corr + rs;
      m = mn;
      ushort4 w0, w1, w2, w3;
      w0.x = f2bf(p[0]);  w0.y = f2bf(p[1]);  w0.z = f2bf(p[2]);  w0.w = f2bf(p[3]);
      w1.x = f2bf(p[4]);  w1.y = f2bf(p[5]);  w1.z = f2bf(p[6]);  w1.w = f2bf(p[7]);
      w2.x = f2bf(p[8]);  w2.y = f2bf(p[9]);  w2.z = f2bf(p[10]); w2.w = f2bf(p[11]);
      w3.x = f2bf(p[12]); w3.y = f2bf(p[13]); w3.z = f2bf(p[14]); w3.w = f2bf(p[15]);
      // per-wave private P region: DS ops are in-order within a wave; the
      // compiler's alias analysis orders the reads below after these writes.
      *(ushort4*)(Pw + l15 * 68 + 4 * g) = w0;
      *(ushort4*)(Pw + l15 * 68 + 16 + 4 * g) = w1;
      *(ushort4*)(Pw + l15 * 68 + 32 + 4 * g) = w2;
      *(ushort4*)(Pw + l15 * 68 + 48 + 4 * g) = w3;
      bf16x8 pb0 = *(const bf16x8*)(Pw + l15 * 68 + 8 * g);
      bf16x8 pb1 = *(const bf16x8*)(Pw + l15 * 68 + 32 + 8 * g);
      bf16x8 av00 = *(const bf16x8*)(VTl + l15 * VP + kc + 8 * g);
      bf16x8 av01 = *(const bf16x8*)(VTl + l15 * VP + kc + 32 + 8 * g);
      bf16x8 av10 = *(const bf16x8*)(VTl + (16 + l15) * VP + kc + 8 * g);
      bf16x8 av11 = *(const bf16x8*)(VTl + (16 + l15) * VP + kc + 32 + 8 * g);
#pragma unroll
      for (int r = 0; r < 4; r++) { o0[r] *= corr; o1[r] *= corr; }
      o0 = __builtin_amdgcn_mfma_f32_16x16x32_bf16(av00, pb0, o0, 0, 0, 0);
      o0 = __builtin_amdgcn_mfma_f32_16x16x32_bf16(av01, pb1, o0, 0, 0, 0);
      o1 = __builtin_amdgcn_mfma_f32_16x16x32_bf16(av10, pb0, o1, 0, 0, 0);
      o1 = __builtin_amdgcn_mfma_f32_16x16x32_bf16(av11, pb1, o1, 0, 0, 0);
    }
    int slot = w * 16 + l15;
    if (slot < nq) {
      int qi = q0 + slot;
      if (lenq > LQ && slot == LQ - 1) qi = q0 + lenq - 1;
      ushort* outp = CtxB + (size_t)qi * H + chb;
      if (nk > 0) {
        float inv = 1.f / s;
        ushort4 v0, v1;
#pragma unroll
        for (int r = 0; r < 4; r++) { ((ushort*)&v0)[r] = f2bf(o0[r] * inv); ((ushort*)&v1)[r] = f2bf(o1[r] * inv); }
        *(ushort4*)(outp + 4 * g) = v0;
        *(ushort4*)(outp + 16 + 4 * g) = v1;
      } else {
        const float* bv = in_proj_b + 2 * H + chb;
        ushort4 v0, v1;
#pragma unroll
        for (int r = 0; r < 4; r++) { ((ushort*)&v0)[r] = f2bf(bv[4 * g + r]); ((ushort*)&v1)[r] = f2bf(bv[16 + 4 * g + r]); }
        *(ushort4*)(outp + 4 * g) = v0;
        *(ushort4*)(outp + 16 + 4 * g) = v1;
      }
    }
  }
}

// ---------------- K3: out-proj + residual + FFN (16-row blocks) ----------------
__global__ __launch_bounds__(256) void k_out_ffn_mfma(
    const ushort* __restrict__ CtxB, const float* __restrict__ edge_attr,
    const int* __restrict__ sq, const int* __restrict__ eb,
    const ushort* __restrict__ Wb, const float* __restrict__ opb,
    const float* __restrict__ b1, const float* __restrict__ b2,
    float* __restrict__ out) {
  constexpr int IP = 136;  // K=128 pitch
  constexpr int HP = 264;  // K=256 pitch
  __shared__ ushort attB[16 * IP];  // ctx staging, then att bf16
  __shared__ ushort h1L[16 * HP];   // h1 bf16
  const int t = threadIdx.x;
  const int row0 = blockIdx.x * 16;

  for (int idx = t; idx < 16 * 16; idx += 256) {
    int r = idx >> 4, c = idx & 15;
    int i = row0 + r;
    int bb = eb[i];
    int qq0 = sq[bb];
    int lenq = sq[bb + 1] - qq0;
    int src = i;
    if (lenq > LQ && (i - qq0) >= LQ - 1) src = qq0 + lenq - 1;
    *(u16x8*)(attB + r * IP + c * 8) = *(const u16x8*)(CtxB + (size_t)src * H + c * 8);
  }
  __syncthreads();

  const int w = t >> 6, lane = t & 63, g = lane >> 4, l15 = lane & 15;
  const int row = row0 + l15;
  bf16x8 ca[4];
#pragma unroll
  for (int kc = 0; kc < 4; kc++)
    ca[kc] = *(const bf16x8*)(attB + l15 * IP + kc * 32 + g * 8);
  __syncthreads();   // attB free for att writes

  // phase A: att = ctx @ opw^T + opb + edge_attr  (2 ct tiles per wave)
  float att[2][4];
#pragma unroll
  for (int ci = 0; ci < 2; ci++) {
    int ct = w * 2 + ci;
    f32x4 acc = {0.f, 0.f, 0.f, 0.f};
#pragma unroll
    for (int kc = 0; kc < 4; kc++) {
      bf16x8 bw = *(const bf16x8*)(Wb + OPW_OFF + (size_t)(ct * 16 + l15) * H + kc * 32 + g * 8);
      acc = __builtin_amdgcn_mfma_f32_16x16x32_bf16(bw, ca[kc], acc, 0, 0, 0);
    }
    int oc = ct * 16 + 4 * g;
    float4 bo = *(const float4*)(opb + oc);
    float4 ea = *(const float4*)(edge_attr + (size_t)row * H + oc);
    ushort4 v;
    att[ci][0] = acc[0] + bo.x + ea.x; v.x = f2bf(att[ci][0]);
    att[ci][1] = acc[1] + bo.y + ea.y; v.y = f2bf(att[ci][1]);
    att[ci][2] = acc[2] + bo.z + ea.z; v.z = f2bf(att[ci][2]);
    att[ci][3] = acc[3] + bo.w + ea.w; v.w = f2bf(att[ci][3]);
    *(ushort4*)(attB + l15 * IP + oc) = v;
  }
  __syncthreads();

  // phase B: h1 = relu(att @ w1^T + b1)  (4 ct tiles per wave)
  bf16x8 aa[4];
#pragma unroll
  for (int kc = 0; kc < 4; kc++)
    aa[kc] = *(const bf16x8*)(attB + l15 * IP + kc * 32 + g * 8);
#pragma unroll
  for (int ci = 0; ci < 4; ci++) {
    int ct = w * 4 + ci;
    f32x4 acc = {0.f, 0.f, 0.f, 0.f};
#pragma unroll
    for (int kc = 0; kc < 4; kc++) {
      bf16x8 bw = *(const bf16x8*)(Wb + W1_OFF + (size_t)(ct * 16 + l15) * H + kc * 32 + g * 8);
      acc = __builtin_amdgcn_mfma_f32_16x16x32_bf16(bw, aa[kc], acc, 0, 0, 0);
    }
    int oc = ct * 16 + 4 * g;
    float4 bb = *(const float4*)(b1 + oc);
    ushort4 v;
    v.x = f2bf(fmaxf(acc[0] + bb.x, 0.f)); v.y = f2bf(fmaxf(acc[1] + bb.y, 0.f));
    v.z = f2bf(fmaxf(acc[2] + bb.z, 0.f)); v.w = f2bf(fmaxf(acc[3] + bb.w, 0.f));
    *(ushort4*)(h1L + l15 * HP + oc) = v;
  }
  __syncthreads();

  // phase C: out = att + h1 @ w2^T + b2  (same 2 ct tiles as phase A)
  bf16x8 ha[8];
#pragma unroll
  for (int kc = 0; kc < 8; kc++)
    ha[kc] = *(const bf16x8*)(h1L + l15 * HP + kc * 32 + g * 8);
#pragma unroll
  for (int ci = 0; ci < 2; ci++) {
    int ct = w * 2 + ci;
    f32x4 acc = {0.f, 0.f, 0.f, 0.f};
#pragma unroll
    for (int kc = 0; kc < 8; kc++) {
      bf16x8 bw = *(const bf16x8*)(Wb + W2_OFF + (size_t)(ct * 16 + l15) * 2 * H + kc * 32 + g * 8);
      acc = __builtin_amdgcn_mfma_f32_16x16x32_bf16(bw, ha[kc], acc, 0, 0, 0);
    }
    int oc = ct * 16 + 4 * g;
    float4 bb = *(const float4*)(b2 + oc);
    float4 o;
    o.x = att[ci][0] + acc[0] + bb.x;
    o.y = att[ci][1] + acc[1] + bb.y;
    o.z = att[ci][2] + acc[2] + bb.z;
    o.w = att[ci][3] + acc[3] + bb.w;
    *(float4*)(out + (size_t)row * H + oc) = o;
  }
}

extern "C" void kernel_launch(void* const* d_in, const int* in_sizes, int n_in,
                              void* d_out, int out_size, void* d_ws, size_t ws_size,
                              hipStream_t stream) {
  const float* edge_attr = (const float*)d_in[1];
  const int*   iel       = (const int*)d_in[2];
  const int*   ieb       = (const int*)d_in[3];
  const int*   eb        = (const int*)d_in[4];
  const float* in_proj_w = (const float*)d_in[5];
  const float* in_proj_b = (const float*)d_in[6];
  const float* opw       = (const float*)d_in[7];
  const float* opb       = (const float*)d_in[8];
  const float* w1        = (const float*)d_in[9];
  const float* b1        = (const float*)d_in[10];
  const float* w2        = (const float*)d_in[11];
  const float* b2        = (const float*)d_in[12];
  float* out = (float*)d_out;

  char* ws = (char*)d_ws;
  int* sq = (int*)ws;
  int* sk = (int*)(ws + 2048);
  ushort* CtxB = (ushort*)(ws + 4096);            // E*H bf16
  ushort* Wb   = CtxB + (size_t)E * H;            // 131072 bf16 weights
  ushort* Eb   = Wb + W_TOTAL;                    // E*H bf16 edge_attr

  k_starts_prep<<<dim3(2177), dim3(256), 0, stream>>>(eb, ieb, sq, sk, in_proj_w, opw, w1, w2, edge_attr, Wb, Eb);
  k_attn_fused<<<dim3(B, NH), dim3(512), 0, stream>>>(Eb, iel, Wb, in_proj_b, sq, sk, CtxB);
  k_out_ffn_mfma<<<dim3(E / 16), dim3(256), 0, stream>>>(CtxB, edge_attr, sq, eb, Wb, opb, b1, b2, out);
}

// Round 15
// 91.718 us; speedup vs baseline: 1.0201x; 1.0201x over previous
//
#include <hip/hip_runtime.h>
#include <hip/hip_bf16.h>

constexpr int B  = 256;
constexpr int E  = 16384;
constexpr int M  = 65536;
constexpr int H  = 128;
constexpr int NH = 4;
constexpr int HD = 32;
constexpr int LQ = 128;
constexpr int LK = 384;

// bf16 weight buffer offsets (elements)
constexpr int WQ_OFF  = 0;
constexpr int WK_OFF  = 16384;
constexpr int WV_OFF  = 32768;
constexpr int OPW_OFF = 49152;
constexpr int W1_OFF  = 65536;
constexpr int W2_OFF  = 98304;
constexpr int W_TOTAL = 131072;

typedef __attribute__((ext_vector_type(8))) short bf16x8;
typedef __attribute__((ext_vector_type(8))) unsigned short u16x8;
typedef __attribute__((ext_vector_type(4))) float f32x4;

__device__ __forceinline__ ushort f2bf(float x) {
  union { float f; unsigned u; } v; v.f = x;
  unsigned r = (v.u + 0x7FFFu + ((v.u >> 16) & 1u)) >> 16;
  return (ushort)r;
}
__device__ __forceinline__ unsigned pack2bf(float a, float b) {
  return (unsigned)f2bf(a) | ((unsigned)f2bf(b) << 16);
}

// ---------------- K1: starts + bf16 weights + bf16 edge_attr copy ----------------
__global__ __launch_bounds__(256) void k_starts_prep(
    const int* __restrict__ eb, const int* __restrict__ ieb,
    int* __restrict__ sq, int* __restrict__ sk,
    const float* __restrict__ in_proj_w, const float* __restrict__ opw,
    const float* __restrict__ w1, const float* __restrict__ w2,
    const float* __restrict__ edge_attr,
    ushort* __restrict__ Wb, ushort* __restrict__ Eb) {
  const int bx = blockIdx.x, t = threadIdx.x;
  if (bx == 0) {
    for (int i = t; i <= B; i += 256) {
      int lo = 0, hi = E;
      while (lo < hi) { int mid = (lo + hi) >> 1; if (eb[mid] < i) lo = mid + 1; else hi = mid; }
      sq[i] = lo;
      lo = 0; hi = M;
      while (lo < hi) { int mid = (lo + hi) >> 1; if (ieb[mid] < i) lo = mid + 1; else hi = mid; }
      sk[i] = lo;
    }
  } else if (bx <= 128) {
    int i = ((bx - 1) * 256 + t) * 4;
    if (i < W_TOTAL) {
      float4 v;
      if (i < OPW_OFF)      v = *(const float4*)(in_proj_w + i);
      else if (i < W1_OFF)  v = *(const float4*)(opw + (i - OPW_OFF));
      else if (i < W2_OFF)  v = *(const float4*)(w1 + (i - W1_OFF));
      else                  v = *(const float4*)(w2 + (i - W2_OFF));
      ushort4 o; o.x = f2bf(v.x); o.y = f2bf(v.y); o.z = f2bf(v.z); o.w = f2bf(v.w);
      *(ushort4*)(Wb + i) = o;
    }
  } else {
    int i = ((bx - 129) * 256 + t) * 4;   // E*H = 2M elems, 2048 blocks
    float4 v = *(const float4*)(edge_attr + i);
    ushort4 o; o.x = f2bf(v.x); o.y = f2bf(v.y); o.z = f2bf(v.z); o.w = f2bf(v.w);
    *(ushort4*)(Eb + i) = o;
  }
}

// ---------------- K2: fused QKV-projection + flash attention ----------------
// grid (B, NH), 512 threads = 8 waves. Wave w owns q-tile w. Q fully in
// registers (shfl repack); P repack via shfl (no LDS). LDS = K + V^T only
// (52.5 KB) for multi-block residency per CU.
__global__ __launch_bounds__(512, 2) void k_attn_fused(
    const ushort* __restrict__ Eb, const int* __restrict__ iel,
    const ushort* __restrict__ Wb, const float* __restrict__ in_proj_b,
    const int* __restrict__ sq, const int* __restrict__ sk,
    ushort* __restrict__ CtxB) {
  constexpr int KP = 36;
  constexpr int VP = 388;
  __shared__ ushort Kl[LK * KP];               // 27648 B
  __shared__ ushort VTl[HD * VP];              // 24832 B

  const int b = blockIdx.x, h = blockIdx.y;
  const int t = threadIdx.x;
  const int q0 = sq[b], lenq = sq[b + 1] - q0;
  const int k0 = sk[b], lenk = sk[b + 1] - k0;
  const int nq = lenq < LQ ? lenq : LQ;
  const int nk = lenk < LK ? lenk : LK;
  const int nkc = (nk + 63) & ~63;     // 64-granular padding
  const int nqt = (nq + 15) >> 4;
  const int nkt = nkc >> 4;

  const int w = t >> 6, lane = t & 63, g = lane >> 4, l15 = lane & 15;
  const int chb = h * HD;               // head channel base (32 ch)
  const ushort4 z4 = {0, 0, 0, 0};

  // ---- Q projection into registers (wave w handles q-tile w, nqt <= 8) ----
  bf16x8 bq = {};
  if (w < nqt) {
    bf16x8 wf[2][4];
#pragma unroll
    for (int ct = 0; ct < 2; ct++)
#pragma unroll
      for (int kc = 0; kc < 4; kc++)
        wf[ct][kc] = *(const bf16x8*)(Wb + WQ_OFF + (size_t)(chb + ct * 16 + l15) * H + kc * 32 + g * 8);
    int slot = w * 16 + l15;
    bool valid = slot < nq;
    int src = q0 + slot;
    if (lenq > LQ && slot == LQ - 1) src = q0 + lenq - 1;
    if (!valid) src = q0;
    bf16x8 rb[4];
#pragma unroll
    for (int kc = 0; kc < 4; kc++)
      rb[kc] = *(const bf16x8*)(Eb + (size_t)src * H + kc * 32 + g * 8);
    unsigned qw[2][2];
#pragma unroll
    for (int ct = 0; ct < 2; ct++) {
      f32x4 acc = {0.f, 0.f, 0.f, 0.f};
#pragma unroll
      for (int kc = 0; kc < 4; kc++)
        acc = __builtin_amdgcn_mfma_f32_16x16x32_bf16(wf[ct][kc], rb[kc], acc, 0, 0, 0);
      float4 bb = *(const float4*)(in_proj_b + chb + ct * 16 + 4 * g);
      qw[ct][0] = pack2bf(acc[0] + bb.x, acc[1] + bb.y);
      qw[ct][1] = pack2bf(acc[2] + bb.z, acc[3] + bb.w);
    }
    // repack D-layout -> B-frag: bq.dw[j] = channels (8g+2j, 8g+2j+1) of q=l15
    union { int i[4]; bf16x8 v; } bqd;
#pragma unroll
    for (int j = 0; j < 4; j++) {
      int s = (2 * (g & 1) + (j >> 1)) * 16 + l15;
      int lo = __shfl((int)qw[0][j & 1], s);
      int hi = __shfl((int)qw[1][j & 1], s);
      bqd.i[j] = (g < 2) ? lo : hi;
    }
    bq = bqd.v;
  }

  // ---- K,V projection: kt tiles split across 8 waves ----
  {
    bf16x8 wkf[2][4], wvf[2][4];
#pragma unroll
    for (int ct = 0; ct < 2; ct++)
#pragma unroll
      for (int kc = 0; kc < 4; kc++) {
        wkf[ct][kc] = *(const bf16x8*)(Wb + WK_OFF + (size_t)(chb + ct * 16 + l15) * H + kc * 32 + g * 8);
        wvf[ct][kc] = *(const bf16x8*)(Wb + WV_OFF + (size_t)(chb + ct * 16 + l15) * H + kc * 32 + g * 8);
      }
    for (int kt = w; kt < nkt; kt += 8) {
      int slot = kt * 16 + l15;
      bool valid = slot < nk;
      int src = 0;
      if (valid) {
        int kj = k0 + slot;
        if (lenk > LK && slot == LK - 1) kj = k0 + lenk - 1;
        src = iel[kj];
      }
      bf16x8 rb[4];
#pragma unroll
      for (int kc = 0; kc < 4; kc++)
        rb[kc] = *(const bf16x8*)(Eb + (size_t)src * H + kc * 32 + g * 8);
      // K -> Kl row-major
#pragma unroll
      for (int ct = 0; ct < 2; ct++) {
        f32x4 acc = {0.f, 0.f, 0.f, 0.f};
#pragma unroll
        for (int kc = 0; kc < 4; kc++)
          acc = __builtin_amdgcn_mfma_f32_16x16x32_bf16(wkf[ct][kc], rb[kc], acc, 0, 0, 0);
        ushort4 v = z4;
        if (valid) {
          float4 bb = *(const float4*)(in_proj_b + H + chb + ct * 16 + 4 * g);
          v.x = f2bf(acc[0] + bb.x); v.y = f2bf(acc[1] + bb.y);
          v.z = f2bf(acc[2] + bb.z); v.w = f2bf(acc[3] + bb.w);
        }
        *(ushort4*)(Kl + (kt * 16 + l15) * KP + ct * 16 + 4 * g) = v;
      }
      // V -> VTl transposed (channel rows); pads zeroed
#pragma unroll
      for (int ct = 0; ct < 2; ct++) {
        f32x4 acc = {0.f, 0.f, 0.f, 0.f};
#pragma unroll
        for (int kc = 0; kc < 4; kc++)
          acc = __builtin_amdgcn_mfma_f32_16x16x32_bf16(wvf[ct][kc], rb[kc], acc, 0, 0, 0);
        if (valid) {
          float4 bb = *(const float4*)(in_proj_b + 2 * H + chb + ct * 16 + 4 * g);
          VTl[(ct * 16 + 4 * g + 0) * VP + kt * 16 + l15] = f2bf(acc[0] + bb.x);
          VTl[(ct * 16 + 4 * g + 1) * VP + kt * 16 + l15] = f2bf(acc[1] + bb.y);
          VTl[(ct * 16 + 4 * g + 2) * VP + kt * 16 + l15] = f2bf(acc[2] + bb.z);
          VTl[(ct * 16 + 4 * g + 3) * VP + kt * 16 + l15] = f2bf(acc[3] + bb.w);
        } else {
#pragma unroll
          for (int r = 0; r < 4; r++)
            VTl[(ct * 16 + 4 * g + r) * VP + kt * 16 + l15] = 0;
        }
      }
    }
  }
  __syncthreads();

  // ---- flash attention: wave w owns q-tile w; no block barriers ----
  if (w < nqt) {
    const float scale = 0.17677669529663687f;  // 1/sqrt(32)
    f32x4 o0 = {0.f, 0.f, 0.f, 0.f}, o1 = {0.f, 0.f, 0.f, 0.f};
    float m = -3.0e38f, s = 0.f;
    bf16x8 a0 = {}, a1 = {}, a2 = {}, a3 = {};
    if (nk > 0) {
      a0 = *(const bf16x8*)(Kl + (l15) * KP + g * 8);
      a1 = *(const bf16x8*)(Kl + (16 + l15) * KP + g * 8);
      a2 = *(const bf16x8*)(Kl + (32 + l15) * KP + g * 8);
      a3 = *(const bf16x8*)(Kl + (48 + l15) * KP + g * 8);
    }
    for (int kc = 0; kc < nk; kc += 64) {
      f32x4 z = {0.f, 0.f, 0.f, 0.f};
      f32x4 st0 = __builtin_amdgcn_mfma_f32_16x16x32_bf16(a0, bq, z, 0, 0, 0);
      f32x4 st1 = __builtin_amdgcn_mfma_f32_16x16x32_bf16(a1, bq, z, 0, 0, 0);
      f32x4 st2 = __builtin_amdgcn_mfma_f32_16x16x32_bf16(a2, bq, z, 0, 0, 0);
      f32x4 st3 = __builtin_amdgcn_mfma_f32_16x16x32_bf16(a3, bq, z, 0, 0, 0);
      // prefetch next chunk's K A-frags (independent; hides under softmax)
      if (kc + 64 < nk) {
        a0 = *(const bf16x8*)(Kl + (kc + 64 + l15) * KP + g * 8);
        a1 = *(const bf16x8*)(Kl + (kc + 80 + l15) * KP + g * 8);
        a2 = *(const bf16x8*)(Kl + (kc + 96 + l15) * KP + g * 8);
        a3 = *(const bf16x8*)(Kl + (kc + 112 + l15) * KP + g * 8);
      }
      float p[16];
#pragma unroll
      for (int r = 0; r < 4; r++) {
        p[r]      = (kc + 4 * g + r < nk)      ? st0[r] * scale : -1e30f;
        p[4 + r]  = (kc + 16 + 4 * g + r < nk) ? st1[r] * scale : -1e30f;
        p[8 + r]  = (kc + 32 + 4 * g + r < nk) ? st2[r] * scale : -1e30f;
        p[12 + r] = (kc + 48 + 4 * g + r < nk) ? st3[r] * scale : -1e30f;
      }
      float pm = p[0];
#pragma unroll
      for (int r = 1; r < 16; r++) pm = fmaxf(pm, p[r]);
      pm = fmaxf(pm, __shfl_xor(pm, 16));
      pm = fmaxf(pm, __shfl_xor(pm, 32));
      float mn = fmaxf(m, pm);
      float corr = __expf(m - mn);
      float rs = 0.f;
#pragma unroll
      for (int r = 0; r < 16; r++) { p[r] = __expf(p[r] - mn); rs += p[r]; }
      rs += __shfl_xor(rs, 16);
      rs += __shfl_xor(rs, 32);
      s = s * corr + rs;
      m = mn;
      // pack p -> 8 dwords (kk = 16i + 4g + {0..3} lives in pkw[i])
      unsigned pkw[4][2];
#pragma unroll
      for (int i = 0; i < 4; i++) {
        pkw[i][0] = pack2bf(p[4 * i + 0], p[4 * i + 1]);
        pkw[i][1] = pack2bf(p[4 * i + 2], p[4 * i + 3]);
      }
      // repack to B-frags: pb0 = kk 0..31, pb1 = kk 32..63 (per q=l15)
      union { int i[4]; bf16x8 v; } pb0, pb1;
#pragma unroll
      for (int j = 0; j < 4; j++) {
        int sl = (2 * (g & 1) + (j >> 1)) * 16 + l15;
        int a_ = __shfl((int)pkw[0][j & 1], sl);
        int b_ = __shfl((int)pkw[1][j & 1], sl);
        int c_ = __shfl((int)pkw[2][j & 1], sl);
        int d_ = __shfl((int)pkw[3][j & 1], sl);
        pb0.i[j] = (g < 2) ? a_ : b_;
        pb1.i[j] = (g < 2) ? c_ : d_;
      }
      bf16x8 av00 = *(const bf16x8*)(VTl + l15 * VP + kc + 8 * g);
      bf16x8 av01 = *(const bf16x8*)(VTl + l15 * VP + kc + 32 + 8 * g);
      bf16x8 av10 = *(const bf16x8*)(VTl + (16 + l15) * VP + kc + 8 * g);
      bf16x8 av11 = *(const bf16x8*)(VTl + (16 + l15) * VP + kc + 32 + 8 * g);
#pragma unroll
      for (int r = 0; r < 4; r++) { o0[r] *= corr; o1[r] *= corr; }
      o0 = __builtin_amdgcn_mfma_f32_16x16x32_bf16(av00, pb0.v, o0, 0, 0, 0);
      o0 = __builtin_amdgcn_mfma_f32_16x16x32_bf16(av01, pb1.v, o0, 0, 0, 0);
      o1 = __builtin_amdgcn_mfma_f32_16x16x32_bf16(av10, pb0.v, o1, 0, 0, 0);
      o1 = __builtin_amdgcn_mfma_f32_16x16x32_bf16(av11, pb1.v, o1, 0, 0, 0);
    }
    int slot = w * 16 + l15;
    if (slot < nq) {
      int qi = q0 + slot;
      if (lenq > LQ && slot == LQ - 1) qi = q0 + lenq - 1;
      ushort* outp = CtxB + (size_t)qi * H + chb;
      if (nk > 0) {
        float inv = 1.f / s;
        ushort4 v0, v1;
#pragma unroll
        for (int r = 0; r < 4; r++) { ((ushort*)&v0)[r] = f2bf(o0[r] * inv); ((ushort*)&v1)[r] = f2bf(o1[r] * inv); }
        *(ushort4*)(outp + 4 * g) = v0;
        *(ushort4*)(outp + 16 + 4 * g) = v1;
      } else {
        const float* bv = in_proj_b + 2 * H + chb;
        ushort4 v0, v1;
#pragma unroll
        for (int r = 0; r < 4; r++) { ((ushort*)&v0)[r] = f2bf(bv[4 * g + r]); ((ushort*)&v1)[r] = f2bf(bv[16 + 4 * g + r]); }
        *(ushort4*)(outp + 4 * g) = v0;
        *(ushort4*)(outp + 16 + 4 * g) = v1;
      }
    }
  }
}

// ---------------- K3: out-proj + residual + FFN (16-row blocks) ----------------
__global__ __launch_bounds__(256) void k_out_ffn_mfma(
    const ushort* __restrict__ CtxB, const float* __restrict__ edge_attr,
    const int* __restrict__ sq, const int* __restrict__ eb,
    const ushort* __restrict__ Wb, const float* __restrict__ opb,
    const float* __restrict__ b1, const float* __restrict__ b2,
    float* __restrict__ out) {
  constexpr int IP = 136;  // K=128 pitch
  constexpr int HP = 264;  // K=256 pitch
  __shared__ ushort attB[16 * IP];  // ctx staging, then att bf16
  __shared__ ushort h1L[16 * HP];   // h1 bf16
  const int t = threadIdx.x;
  const int row0 = blockIdx.x * 16;

  for (int idx = t; idx < 16 * 16; idx += 256) {
    int r = idx >> 4, c = idx & 15;
    int i = row0 + r;
    int bb = eb[i];
    int qq0 = sq[bb];
    int lenq = sq[bb + 1] - qq0;
    int src = i;
    if (lenq > LQ && (i - qq0) >= LQ - 1) src = qq0 + lenq - 1;
    *(u16x8*)(attB + r * IP + c * 8) = *(const u16x8*)(CtxB + (size_t)src * H + c * 8);
  }
  __syncthreads();

  const int w = t >> 6, lane = t & 63, g = lane >> 4, l15 = lane & 15;
  const int row = row0 + l15;
  bf16x8 ca[4];
#pragma unroll
  for (int kc = 0; kc < 4; kc++)
    ca[kc] = *(const bf16x8*)(attB + l15 * IP + kc * 32 + g * 8);
  __syncthreads();   // attB free for att writes

  // phase A: att = ctx @ opw^T + opb + edge_attr  (2 ct tiles per wave)
  float att[2][4];
#pragma unroll
  for (int ci = 0; ci < 2; ci++) {
    int ct = w * 2 + ci;
    f32x4 acc = {0.f, 0.f, 0.f, 0.f};
#pragma unroll
    for (int kc = 0; kc < 4; kc++) {
      bf16x8 bw = *(const bf16x8*)(Wb + OPW_OFF + (size_t)(ct * 16 + l15) * H + kc * 32 + g * 8);
      acc = __builtin_amdgcn_mfma_f32_16x16x32_bf16(bw, ca[kc], acc, 0, 0, 0);
    }
    int oc = ct * 16 + 4 * g;
    float4 bo = *(const float4*)(opb + oc);
    float4 ea = *(const float4*)(edge_attr + (size_t)row * H + oc);
    ushort4 v;
    att[ci][0] = acc[0] + bo.x + ea.x; v.x = f2bf(att[ci][0]);
    att[ci][1] = acc[1] + bo.y + ea.y; v.y = f2bf(att[ci][1]);
    att[ci][2] = acc[2] + bo.z + ea.z; v.z = f2bf(att[ci][2]);
    att[ci][3] = acc[3] + bo.w + ea.w; v.w = f2bf(att[ci][3]);
    *(ushort4*)(attB + l15 * IP + oc) = v;
  }
  __syncthreads();

  // phase B: h1 = relu(att @ w1^T + b1)  (4 ct tiles per wave)
  bf16x8 aa[4];
#pragma unroll
  for (int kc = 0; kc < 4; kc++)
    aa[kc] = *(const bf16x8*)(attB + l15 * IP + kc * 32 + g * 8);
#pragma unroll
  for (int ci = 0; ci < 4; ci++) {
    int ct = w * 4 + ci;
    f32x4 acc = {0.f, 0.f, 0.f, 0.f};
#pragma unroll
    for (int kc = 0; kc < 4; kc++) {
      bf16x8 bw = *(const bf16x8*)(Wb + W1_OFF + (size_t)(ct * 16 + l15) * H + kc * 32 + g * 8);
      acc = __builtin_amdgcn_mfma_f32_16x16x32_bf16(bw, aa[kc], acc, 0, 0, 0);
    }
    int oc = ct * 16 + 4 * g;
    float4 bb = *(const float4*)(b1 + oc);
    ushort4 v;
    v.x = f2bf(fmaxf(acc[0] + bb.x, 0.f)); v.y = f2bf(fmaxf(acc[1] + bb.y, 0.f));
    v.z = f2bf(fmaxf(acc[2] + bb.z, 0.f)); v.w = f2bf(fmaxf(acc[3] + bb.w, 0.f));
    *(ushort4*)(h1L + l15 * HP + oc) = v;
  }
  __syncthreads();

  // phase C: out = att + h1 @ w2^T + b2  (same 2 ct tiles as phase A)
  bf16x8 ha[8];
#pragma unroll
  for (int kc = 0; kc < 8; kc++)
    ha[kc] = *(const bf16x8*)(h1L + l15 * HP + kc * 32 + g * 8);
#pragma unroll
  for (int ci = 0; ci < 2; ci++) {
    int ct = w * 2 + ci;
    f32x4 acc = {0.f, 0.f, 0.f, 0.f};
#pragma unroll
    for (int kc = 0; kc < 8; kc++) {
      bf16x8 bw = *(const bf16x8*)(Wb + W2_OFF + (size_t)(ct * 16 + l15) * 2 * H + kc * 32 + g * 8);
      acc = __builtin_amdgcn_mfma_f32_16x16x32_bf16(bw, ha[kc], acc, 0, 0, 0);
    }
    int oc = ct * 16 + 4 * g;
    float4 bb = *(const float4*)(b2 + oc);
    float4 o;
    o.x = att[ci][0] + acc[0] + bb.x;
    o.y = att[ci][1] + acc[1] + bb.y;
    o.z = att[ci][2] + acc[2] + bb.z;
    o.w = att[ci][3] + acc[3] + bb.w;
    *(float4*)(out + (size_t)row * H + oc) = o;
  }
}

extern "C" void kernel_launch(void* const* d_in, const int* in_sizes, int n_in,
                              void* d_out, int out_size, void* d_ws, size_t ws_size,
                              hipStream_t stream) {
  const float* edge_attr = (const float*)d_in[1];
  const int*   iel       = (const int*)d_in[2];
  const int*   ieb       = (const int*)d_in[3];
  const int*   eb        = (const int*)d_in[4];
  const float* in_proj_w = (const float*)d_in[5];
  const float* in_proj_b = (const float*)d_in[6];
  const float* opw       = (const float*)d_in[7];
  const float* opb       = (const float*)d_in[8];
  const float* w1        = (const float*)d_in[9];
  const float* b1        = (const float*)d_in[10];
  const float* w2        = (const float*)d_in[11];
  const float* b2        = (const float*)d_in[12];
  float* out = (float*)d_out;

  char* ws = (char*)d_ws;
  int* sq = (int*)ws;
  int* sk = (int*)(ws + 2048);
  ushort* CtxB = (ushort*)(ws + 4096);            // E*H bf16
  ushort* Wb   = CtxB + (size_t)E * H;            // 131072 bf16 weights
  ushort* Eb   = Wb + W_TOTAL;                    // E*H bf16 edge_attr

  k_starts_prep<<<dim3(2177), dim3(256), 0, stream>>>(eb, ieb, sq, sk, in_proj_w, opw, w1, w2, edge_attr, Wb, Eb);
  k_attn_fused<<<dim3(B, NH), dim3(512), 0, stream>>>(Eb, iel, Wb, in_proj_b, sq, sk, CtxB);
  k_out_ffn_mfma<<<dim3(E / 16), dim3(256), 0, stream>>>(CtxB, edge_attr, sq, eb, Wb, opb, b1, b2, out);
}